// Round 1
// baseline (278.274 us; speedup 1.0000x reference)
//
#include <hip/hip_runtime.h>

// Problem constants
#define BATCH 512
#define HWIMG 78400      // 280*280
#define WROW  280
#define KSZ   28
#define PNUM  100        // 10x10 patches
#define FNUM  16
#define ONUM  10

__global__ __launch_bounds__(256) void init_out(const float* __restrict__ dec_b,
                                                float* __restrict__ out) {
    int i = blockIdx.x * 256 + threadIdx.x;
    if (i < BATCH * ONUM) out[i] = dec_b[i % ONUM];
}

// Block: one patch p, 32 batches. 128 threads = bg(4) x fg(4) x kg(8).
// Per-thread register tile: 8 batches x 4 filters, k-sliced by kg (float4 each).
__global__ __launch_bounds__(128, 4) void lcn_fused(
    const float* __restrict__ x,      // (512,1,280,280)
    const float* __restrict__ weight, // (1600,1,28,28)  index (f*100+p)*784
    const float* __restrict__ bias,   // (1600,1)        index  f*100+p
    const float* __restrict__ dec_w,  // (10,1600)       index  o*1600+f*100+p
    float* __restrict__ out)          // (512,10) pre-initialized with dec_b
{
    const int t  = threadIdx.x;
    const int kg = t & 7;           // k-slice group (lane bits 0..2)
    const int fg = (t >> 3) & 3;    // filter group  (lane bits 3..4)
    const int bg = t >> 5;          // batch group   0..3
    const int bx = blockIdx.x;
    const int p  = bx >> 4;         // 0..99  (16 consecutive blocks share p -> warm W)
    const int bt = bx & 15;         // batch tile 0..15
    const int pr = p / 10, pc = p % 10;
    const int b0 = bt * 32 + bg * 8;

    // kg==7 would read k=28..31 (past the patch row): clamp to 24 and zero later.
    const int kq = (kg < 7) ? kg * 4 : 24;

    const float* xp[8];
#pragma unroll
    for (int i = 0; i < 8; ++i)
        xp[i] = x + (size_t)(b0 + i) * HWIMG + (size_t)pr * 28 * WROW + pc * 28 + kq;

    const float* wp[4];
#pragma unroll
    for (int j = 0; j < 4; ++j)
        wp[j] = weight + (size_t)((fg * 4 + j) * PNUM + p) * 784 + kq;

    float acc[8][4];
#pragma unroll
    for (int i = 0; i < 8; ++i)
#pragma unroll
        for (int j = 0; j < 4; ++j) acc[i][j] = 0.f;

#pragma unroll 2
    for (int kr = 0; kr < KSZ; ++kr) {
        float4 av[8];
#pragma unroll
        for (int i = 0; i < 8; ++i)
            av[i] = *reinterpret_cast<const float4*>(xp[i] + kr * WROW);
        float4 wv[4];
#pragma unroll
        for (int j = 0; j < 4; ++j)
            wv[j] = *reinterpret_cast<const float4*>(wp[j] + kr * KSZ);
#pragma unroll
        for (int i = 0; i < 8; ++i) {
#pragma unroll
            for (int j = 0; j < 4; ++j) {
                acc[i][j] = fmaf(av[i].x, wv[j].x, acc[i][j]);
                acc[i][j] = fmaf(av[i].y, wv[j].y, acc[i][j]);
                acc[i][j] = fmaf(av[i].z, wv[j].z, acc[i][j]);
                acc[i][j] = fmaf(av[i].w, wv[j].w, acc[i][j]);
            }
        }
    }

    // kg==7 computed on duplicated data: zero it.
    const float km = (kg < 7) ? 1.f : 0.f;
#pragma unroll
    for (int i = 0; i < 8; ++i)
#pragma unroll
        for (int j = 0; j < 4; ++j) acc[i][j] *= km;

    // Reduce over kg (lane bits 0..2) — butterfly, all lanes end with the sum.
#pragma unroll
    for (int d = 1; d < 8; d <<= 1)
#pragma unroll
        for (int i = 0; i < 8; ++i)
#pragma unroll
            for (int j = 0; j < 4; ++j)
                acc[i][j] += __shfl_xor(acc[i][j], d, 64);

    // bias + relu
    float y[8][4];
#pragma unroll
    for (int j = 0; j < 4; ++j) {
        const float bs = bias[(fg * 4 + j) * PNUM + p];
#pragma unroll
        for (int i = 0; i < 8; ++i) {
            float v = acc[i][j] + bs;
            y[i][j] = v > 0.f ? v : 0.f;
        }
    }

    // Decoder: split the 10 outputs across kg lanes 0..4 (2 outputs each).
    float po[8][2];
    float dwv[4][2];
    const int  o0  = kg * 2;
    const bool act = (kg < 5);
    if (act) {
#pragma unroll
        for (int j = 0; j < 4; ++j)
#pragma unroll
            for (int oo = 0; oo < 2; ++oo)
                dwv[j][oo] = dec_w[(size_t)(o0 + oo) * (PNUM * FNUM) + (fg * 4 + j) * PNUM + p];
#pragma unroll
        for (int i = 0; i < 8; ++i)
#pragma unroll
            for (int oo = 0; oo < 2; ++oo) {
                float s = 0.f;
#pragma unroll
                for (int j = 0; j < 4; ++j) s = fmaf(y[i][j], dwv[j][oo], s);
                po[i][oo] = s;
            }
    } else {
#pragma unroll
        for (int i = 0; i < 8; ++i) { po[i][0] = 0.f; po[i][1] = 0.f; }
    }

    // Reduce over fg (lane bits 3..4); kg bits preserved so zero lanes stay isolated.
#pragma unroll
    for (int d = 8; d < 32; d <<= 1)
#pragma unroll
        for (int i = 0; i < 8; ++i)
#pragma unroll
            for (int oo = 0; oo < 2; ++oo)
                po[i][oo] += __shfl_xor(po[i][oo], d, 64);

    if (act && fg == 0) {
#pragma unroll
        for (int i = 0; i < 8; ++i)
#pragma unroll
            for (int oo = 0; oo < 2; ++oo)
                atomicAdd(&out[(size_t)(b0 + i) * ONUM + o0 + oo], po[i][oo]);
    }
}

extern "C" void kernel_launch(void* const* d_in, const int* in_sizes, int n_in,
                              void* d_out, int out_size, void* d_ws, size_t ws_size,
                              hipStream_t stream) {
    const float* x     = (const float*)d_in[0];
    const float* w     = (const float*)d_in[1];
    const float* bias  = (const float*)d_in[2];
    const float* dec_w = (const float*)d_in[3];
    const float* dec_b = (const float*)d_in[4];
    float* out = (float*)d_out;

    init_out<<<(BATCH * ONUM + 255) / 256, 256, 0, stream>>>(dec_b, out);
    lcn_fused<<<(BATCH / 32) * PNUM, 128, 0, stream>>>(x, w, bias, dec_w, out);
}